// Round 9
// baseline (1197.658 us; speedup 1.0000x reference)
//
#include <hip/hip_runtime.h>
#include <hip/hip_bf16.h>
#include <cstdint>
#include <cstddef>

typedef __attribute__((ext_vector_type(8))) short bf16x8;
typedef __attribute__((ext_vector_type(4))) float f32x4;
typedef __attribute__((ext_vector_type(16))) float f32x16;
typedef __attribute__((ext_vector_type(4))) int i32x4;
typedef __attribute__((ext_vector_type(8))) int i32x8;
typedef __attribute__((ext_vector_type(4))) uint16_t u16x4;
typedef __attribute__((ext_vector_type(8))) uint16_t u16x8;

#define GLOBAL_AS __attribute__((address_space(1)))
#define LDS_AS __attribute__((address_space(3)))

__device__ inline uint16_t f2b(float f) {
    uint32_t x = __float_as_uint(f);
    uint32_t r = (x + 0x7fffu + ((x >> 16) & 1u)) >> 16;
    return (uint16_t)r;
}

// ---------------------------------------------------------------- convert fp32 -> fp8 e4m3 (x64 prescale)
__global__ void cvt8_kernel(const float* __restrict__ in, uint2* __restrict__ out, size_t n8) {
    size_t stride = (size_t)gridDim.x * blockDim.x;
    for (size_t i = (size_t)blockIdx.x * blockDim.x + threadIdx.x; i < n8; i += stride) {
        const float4* p = (const float4*)(in + i * 8);
        float4 a = p[0], b = p[1];
        int w0 = __builtin_amdgcn_cvt_pk_fp8_f32(a.x * 64.f, a.y * 64.f, 0, false);
        w0 = __builtin_amdgcn_cvt_pk_fp8_f32(a.z * 64.f, a.w * 64.f, w0, true);
        int w1 = __builtin_amdgcn_cvt_pk_fp8_f32(b.x * 64.f, b.y * 64.f, 0, false);
        w1 = __builtin_amdgcn_cvt_pk_fp8_f32(b.z * 64.f, b.w * 64.f, w1, true);
        out[i] = make_uint2((unsigned)w0, (unsigned)w1);
    }
}

// ---------------------------------------------------------------- fp8 MX GEMM + fused LSE partials
// R9 = R8 structure with a SLOT-PLANE LDS layout (k-major):
//   addr(row, slot16) = slot*PLANE + row*16   (A: PLANE=4096 [256 rows], B: 2048 [128 rows])
// Every ds_read_b128 is then 512 B CONTIGUOUS per half-wave (stride-1, the
// measured-zero-conflict pattern) — no XOR swizzle anywhere. Staging keeps
// linear global_load_lds dests; per-lane global src = (chunk*64+lane)*H + s*16.
// Main loop schedule/ledger identical to R7/R8: tile 256x128, 8 waves 4Mx2N,
// per-wave 64x64 (acc=64 AGPR), BK=64, 3 buffers, stage t+2, vmcnt(3), 1 barrier.
// Epilogue: R8's conflict-free LDS partial-sum transpose, M=0 partials.

#define SC8 0x7F7F7F7F

#define MFMA8(aa, bb, cc) cc = __builtin_amdgcn_mfma_scale_f32_32x32x64_f8f6f4( \
        aa, bb, cc, 0, 0, 0, SC8, 0, SC8)

__device__ __forceinline__ i32x8 frag_read_p(const char* p0, int plane) {
    // p0 = region + 2*kq*plane + (rowbase+l31)*16 ; second slot one plane up
    i32x4 lo = *(const i32x4*)p0;
    i32x4 hi = *(const i32x4*)(p0 + plane);
    i32x8 f;
    f[0] = lo[0]; f[1] = lo[1]; f[2] = lo[2]; f[3] = lo[3];
    f[4] = hi[0]; f[5] = hi[1]; f[6] = hi[2]; f[7] = hi[3];
    return f;
}

__global__ __launch_bounds__(512, 4)
void flce_gemm_fp8(const uint8_t* __restrict__ X8, const uint8_t* __restrict__ W8,
                   const long long* __restrict__ target,
                   float2* __restrict__ partials, float* __restrict__ tgt_logit,
                   int BT, int H, int V, int nrb) {
    __shared__ __align__(16) char smem[73728];   // A: 3 x 16KB, B: 3 x 8KB
#define ARG(i) (smem + (i) * 16384)
#define BRG(i) (smem + 49152 + (i) * 8192)

    const int tid = threadIdx.x;
    const int lane = tid & 63, wave = tid >> 6;
    const int wr = wave >> 1, wc = wave & 1;     // 4(M) x 2(N)
    const int l31 = lane & 31;
    const int kq = lane >> 5;                    // fragment k-half (0/1)
    const int NT = H / 64;

    // bijective XCD swizzle (m204), rb-fastest (nwg=4000, %8==0)
    const int nwg = gridDim.x;
    const int q = nwg >> 3, rres = nwg & 7;
    const int xcd = blockIdx.x & 7, idx = blockIdx.x >> 3;
    const int wgid = (xcd < rres ? xcd * (q + 1) : rres * (q + 1) + (xcd - rres) * q) + idx;
    const int rb = wgid % nrb, cb = wgid / nrb;
    const int brow = rb * 256, bcol = cb * 128;

    const uint8_t* XA = X8 + (size_t)brow * H;
    const uint8_t* WB = W8 + (size_t)bcol * H;

    // ---- staging offsets (slot-plane layout) ----
    // A (256 rows, 4 slot-planes of 4096 B): wave w covers s=w>>1, chunks {2(w&1), 2(w&1)+1}
    // B (128 rows, 4 slot-planes of 2048 B): wave w covers s=w>>1, chunk w&1
    const int ws = wave >> 1, wh = wave & 1;
    const size_t aSrc0 = (size_t)((wh * 128) + lane) * H + ws * 16;     // chunk 2*wh
    const size_t aSrc1 = aSrc0 + (size_t)64 * H;                         // chunk 2*wh+1
    const int    aDst0 = ws * 4096 + wh * 2048 + lane * 16;
    const int    aDst1 = aDst0 + 1024;
    const size_t bSrc  = (size_t)((wh * 64) + lane) * H + ws * 16;
    const int    bDst  = ws * 2048 + wh * 1024 + lane * 16;

#define STG(gp, lp) __builtin_amdgcn_global_load_lds( \
        (const GLOBAL_AS uint32_t*)(gp), (LDS_AS uint32_t*)(lp), 16, 0, 0)
#define STAGE_TILE(Adst, Bdst, kbyte) do { \
        STG(XA + (kbyte) + aSrc0, (Adst) + aDst0); \
        STG(XA + (kbyte) + aSrc1, (Adst) + aDst1); \
        STG(WB + (kbyte) + bSrc,  (Bdst) + bDst);  \
    } while (0)

    // ---- read offsets (per-lane, constant across tiles) ----
    const int aOff0 = 2 * kq * 4096 + (wr * 64 + l31) * 16;   // a-frag rows wr*64+l31
    const int aOff1 = aOff0 + 512;                            // +32 rows
    const int bOff0 = 2 * kq * 2048 + (wc * 64 + l31) * 16;
    const int bOff1 = bOff0 + 512;

    f32x16 acc00 = {}, acc01 = {}, acc10 = {}, acc11 = {};

    // 3-buffer rotation: Ac/Bc = current (tile t), An/Bn = next, Af/Bf = stage target
    char *Ac = ARG(0), *An = ARG(1), *Af = ARG(2);
    char *Bc = BRG(0), *Bn = BRG(1), *Bf = BRG(2);

    // ---- prologue: stage T0, T1; drain T0; barrier
    STAGE_TILE(Ac, Bc, 0);
    if (NT > 1) {
        STAGE_TILE(An, Bn, 64);
        asm volatile("s_waitcnt vmcnt(3)" ::: "memory");
    } else {
        asm volatile("s_waitcnt vmcnt(0)" ::: "memory");
    }
    __builtin_amdgcn_s_barrier();

    for (int t = 0; t < NT; ++t) {
        // stage tile t+2 into the far buffer (last read in tile t-1; safe)
        if (t + 2 < NT) STAGE_TILE(Af, Bf, (size_t)(t + 2) * 64);

        // JIT fragment reads, stride-1 per half-wave (conflict-free by construction)
        i32x8 aF0 = frag_read_p(Ac + aOff0, 4096);
        i32x8 aF1 = frag_read_p(Ac + aOff1, 4096);
        i32x8 bF0 = frag_read_p(Bc + bOff0, 2048);
        i32x8 bF1 = frag_read_p(Bc + bOff1, 2048);

        __builtin_amdgcn_s_setprio(1);
        MFMA8(aF0, bF0, acc00);
        MFMA8(aF0, bF1, acc01);
        MFMA8(aF1, bF0, acc10);
        MFMA8(aF1, bF1, acc11);
        __builtin_amdgcn_s_setprio(0);

        // end-of-tile: ensure t+1 landed (oldest 3 of 6 outstanding)
        if (t + 2 < NT)      asm volatile("s_waitcnt vmcnt(3)" ::: "memory");
        else if (t + 1 < NT) asm volatile("s_waitcnt vmcnt(0)" ::: "memory");
        __builtin_amdgcn_s_barrier();

        // rotate buffers
        char* ta = Ac; Ac = An; An = Af; Af = ta;
        char* tb = Bc; Bc = Bn; Bn = Bf; Bf = tb;
    }

    // ---- epilogue: conflict-free LDS partial-sum transpose, M=0 partials
    __syncthreads();                              // smem free for reuse
    int* tgt_l = (int*)(smem + 33280);            // 256 ints after the 2 regions
    if (tid < 256) {
        long long tt = target[brow + tid];
        if (tt < 0) tt = 0;
        if (tt >= V) tt = (long long)V - 1;
        tgt_l[tid] = (int)tt;
    }
    __syncthreads();

    const float inv = 1.0f / 4096.0f;
    const int c0 = wc * 64 + l31;
#pragma unroll
    for (int p = 0; p < 2; ++p) {
        if ((wr >> 1) == p) {                      // writers: waves with wr in {2p, 2p+1}
            float* reg = (float*)(smem + (wr & 1) * 16640);   // [64][65]
#pragma unroll
            for (int mi = 0; mi < 2; ++mi) {
                const f32x16* a0 = mi ? &acc10 : &acc00;
                const f32x16* a1 = mi ? &acc11 : &acc01;
#pragma unroll
                for (int j = 0; j < 16; ++j) {
                    int rif = (j & 3) + 8 * (j >> 2) + 4 * kq;
                    int rl = mi * 32 + rif;
                    int grow = wr * 64 + rl;
                    int tc = tgt_l[grow] - bcol;
                    float v0 = (*a0)[j] * inv;
                    float v1 = (*a1)[j] * inv;
                    if (tc == c0) tgt_logit[brow + grow] = v0;
                    if (tc == c0 + 32) tgt_logit[brow + grow] = v1;
                    reg[rl * 65 + wc * 32 + l31] = __expf(v0) + __expf(v1);
                }
            }
        }
        __syncthreads();
        if ((wave >> 1) == p) {                    // readers: waves 2p, 2p+1
            const int rw = wave & 1;
            const float* reg = (const float*)(smem + rw * 16640);
            float S = 0.f;
#pragma unroll
            for (int c = 0; c < 64; ++c) S += reg[lane * 65 + c];
            int grow = (2 * p + rw) * 64 + lane;
            partials[(size_t)cb * BT + brow + grow] = make_float2(0.f, S);
        }
        __syncthreads();
    }
#undef ARG
#undef BRG
#undef STG
#undef STAGE_TILE
}

// ---------------------------------------------------------------- fp32 fallback (128^2, m97 structure)
__global__ void flce_gemm_f32(const float* __restrict__ X, const float* __restrict__ Wf,
                              const long long* __restrict__ target,
                              float2* __restrict__ partials, float* __restrict__ tgt_logit,
                              int BT, int H, int V, int nrb) {
    __shared__ uint16_t As[128 * 32];
    __shared__ uint16_t Bs[128 * 32];
    __shared__ float red_m[128][2];
    __shared__ float red_s[128][2];
    __shared__ int tgt_l[128];

    const int tid = threadIdx.x;
    const int wave = tid >> 6, lane = tid & 63;
    const int wr = wave >> 1, wc = wave & 1;
    const int l16 = lane & 15, lh = lane >> 4;
    const int bid = blockIdx.x;
    const int rb = bid % nrb, cb = bid / nrb;
    const int brow = rb * 128, bcol = cb * 128;

    if (tid < 128) {
        long long t = target[brow + tid];
        if (t < 0) t = 0;
        if (t >= V) t = (long long)V - 1;
        tgt_l[tid] = (int)t;
    }

    f32x4 acc[4][4] = {};
    for (int k0 = 0; k0 < H; k0 += 32) {
        __syncthreads();
#pragma unroll
        for (int j = 0; j < 4; ++j) {
            int fi = tid + j * 256;
            int row = fi >> 3;
            int kk = (fi & 7) << 2;
            float4 av = *(const float4*)(X + (size_t)(brow + row) * H + k0 + kk);
            float4 bv = *(const float4*)(Wf + (size_t)(bcol + row) * H + k0 + kk);
            u16x4 au, bu;
            au[0] = f2b(av.x); au[1] = f2b(av.y); au[2] = f2b(av.z); au[3] = f2b(av.w);
            bu[0] = f2b(bv.x); bu[1] = f2b(bv.y); bu[2] = f2b(bv.z); bu[3] = f2b(bv.w);
            *(u16x4*)&As[row * 32 + kk] = au;
            *(u16x4*)&Bs[row * 32 + kk] = bu;
        }
        __syncthreads();
        bf16x8 af[4], bf[4];
#pragma unroll
        for (int m = 0; m < 4; ++m)
            af[m] = *(const bf16x8*)&As[(wr * 64 + m * 16 + l16) * 32 + lh * 8];
#pragma unroll
        for (int n = 0; n < 4; ++n)
            bf[n] = *(const bf16x8*)&Bs[(wc * 64 + n * 16 + l16) * 32 + lh * 8];
#pragma unroll
        for (int m = 0; m < 4; ++m)
#pragma unroll
            for (int n = 0; n < 4; ++n)
                acc[m][n] = __builtin_amdgcn_mfma_f32_16x16x32_bf16(af[m], bf[n], acc[m][n], 0, 0, 0);
    }
#pragma unroll
    for (int m = 0; m < 4; ++m) {
#pragma unroll
        for (int r = 0; r < 4; ++r) {
            int rowl = wr * 64 + m * 16 + lh * 4 + r;
            int tc = tgt_l[rowl] - bcol;
            float mx = -INFINITY;
#pragma unroll
            for (int n = 0; n < 4; ++n) {
                float v = acc[m][n][r];
                if (tc == wc * 64 + n * 16 + l16) tgt_logit[brow + rowl] = v;
                mx = fmaxf(mx, v);
            }
#pragma unroll
            for (int d = 1; d < 16; d <<= 1) mx = fmaxf(mx, __shfl_xor(mx, d));
            float s = 0.f;
#pragma unroll
            for (int n = 0; n < 4; ++n) s += __expf(acc[m][n][r] - mx);
#pragma unroll
            for (int d = 1; d < 16; d <<= 1) s += __shfl_xor(s, d);
            if (l16 == 0) { red_m[rowl][wc] = mx; red_s[rowl][wc] = s; }
        }
    }
    __syncthreads();
    if (tid < 128) {
        float m0 = red_m[tid][0], m1 = red_m[tid][1];
        float s0 = red_s[tid][0], s1 = red_s[tid][1];
        float M = fmaxf(m0, m1);
        float S = s0 * __expf(m0 - M) + s1 * __expf(m1 - M);
        partials[(size_t)cb * BT + brow + tid] = make_float2(M, S);
    }
}

// ---------------------------------------------------------------- per-row LSE merge + block sums
__global__ void flce_reduce(const float2* __restrict__ partials,
                            const float* __restrict__ tgt_logit,
                            const long long* __restrict__ target,
                            float2* __restrict__ bsums, int BT, int NCB) {
    int row = blockIdx.x * blockDim.x + threadIdx.x;
    float M = -INFINITY, S = 0.f;
    for (int cbi = 0; cbi < NCB; ++cbi) {
        float2 p = partials[(size_t)cbi * BT + row];
        float Mn = fmaxf(M, p.x);
        S = S * __expf(M - Mn) + p.y * __expf(p.x - Mn);
        M = Mn;
    }
    float lse = M + __logf(S);
    bool valid = (target[row] != -100);
    float nll = valid ? (lse - tgt_logit[row]) : 0.f;
    float cnt = valid ? 1.f : 0.f;
#pragma unroll
    for (int d = 1; d < 64; d <<= 1) { nll += __shfl_xor(nll, d); cnt += __shfl_xor(cnt, d); }
    __shared__ float sm[8][2];
    int w = threadIdx.x >> 6;
    if ((threadIdx.x & 63) == 0) { sm[w][0] = nll; sm[w][1] = cnt; }
    __syncthreads();
    if (threadIdx.x == 0) {
        float sn = 0.f, sc = 0.f;
        int nw = blockDim.x >> 6;
        for (int i = 0; i < nw; ++i) { sn += sm[i][0]; sc += sm[i][1]; }
        bsums[blockIdx.x] = make_float2(sn, sc);
    }
}

__global__ void flce_final(const float2* __restrict__ bsums, int nb, float* __restrict__ out) {
    if (blockIdx.x == 0 && threadIdx.x == 0) {
        float sn = 0.f, sc = 0.f;
        for (int i = 0; i < nb; ++i) { sn += bsums[i].x; sc += bsums[i].y; }
        out[0] = sn / sc;
    }
}

// ---------------------------------------------------------------- launch
extern "C" void kernel_launch(void* const* d_in, const int* in_sizes, int n_in,
                              void* d_out, int out_size, void* d_ws, size_t ws_size,
                              hipStream_t stream) {
    const float* x = (const float*)d_in[0];
    const float* w = (const float*)d_in[1];
    const long long* target = (const long long*)d_in[2];
    float* out = (float*)d_out;

    const int BT = in_sizes[2];
    const int H = in_sizes[0] / BT;
    const int V = in_sizes[1] / H;
    const int nred = BT / 256;

    char* ws = (char*)d_ws;
    size_t szW = (size_t)V * H;            // fp8: 1 B/elem
    size_t szX = (size_t)BT * H;
    const int nrb = BT / 256;              // 16
    const int ncb = V / 128;               // 250
    size_t szPart = (size_t)ncb * BT * sizeof(float2);
    size_t szTgt = (size_t)BT * sizeof(float);
    size_t szB = (size_t)nred * sizeof(float2);

    bool use8 = ws_size >= szW + szX + szPart + szTgt + szB;

    if (use8) {
        uint8_t* W8 = (uint8_t*)ws;
        uint8_t* X8 = (uint8_t*)(ws + szW);
        float2* partials = (float2*)(ws + szW + szX);
        float* tgtlog = (float*)(ws + szW + szX + szPart);
        float2* bsums = (float2*)(ws + szW + szX + szPart + szTgt);

        hipLaunchKernelGGL(cvt8_kernel, dim3(1024), dim3(256), 0, stream,
                           x, (uint2*)X8, (size_t)BT * H / 8);
        hipLaunchKernelGGL(cvt8_kernel, dim3(4096), dim3(256), 0, stream,
                           w, (uint2*)W8, (size_t)V * H / 8);
        hipLaunchKernelGGL(flce_gemm_fp8, dim3(nrb * ncb), dim3(512), 0, stream,
                           X8, W8, target, partials, tgtlog, BT, H, V, nrb);
        hipLaunchKernelGGL(flce_reduce, dim3(BT / 256), dim3(256), 0, stream,
                           partials, tgtlog, target, bsums, BT, ncb);
        hipLaunchKernelGGL(flce_final, dim3(1), dim3(64), 0, stream, bsums, nred, out);
    } else {
        const int nrb1 = BT / 128, ncb1 = V / 128;
        float2* partials = (float2*)ws;
        float* tgtlog = (float*)(ws + (size_t)ncb1 * BT * sizeof(float2));
        float2* bsums = (float2*)(ws + (size_t)ncb1 * BT * sizeof(float2) + szTgt);
        hipLaunchKernelGGL(flce_gemm_f32, dim3(nrb1 * ncb1), dim3(256), 0, stream,
                           x, w, target, partials, tgtlog, BT, H, V, nrb1);
        hipLaunchKernelGGL(flce_reduce, dim3(BT / 256), dim3(256), 0, stream,
                           partials, tgtlog, target, bsums, BT, ncb1);
        hipLaunchKernelGGL(flce_final, dim3(1), dim3(64), 0, stream, bsums, nred, out);
    }
}

// Round 10
// 713.572 us; speedup vs baseline: 1.6784x; 1.6784x over previous
//
#include <hip/hip_runtime.h>
#include <hip/hip_bf16.h>
#include <cstdint>
#include <cstddef>

typedef __attribute__((ext_vector_type(8))) short bf16x8;
typedef __attribute__((ext_vector_type(4))) float f32x4;
typedef __attribute__((ext_vector_type(16))) float f32x16;
typedef __attribute__((ext_vector_type(4))) int i32x4;
typedef __attribute__((ext_vector_type(8))) int i32x8;
typedef __attribute__((ext_vector_type(4))) uint16_t u16x4;
typedef __attribute__((ext_vector_type(8))) uint16_t u16x8;

#define GLOBAL_AS __attribute__((address_space(1)))
#define LDS_AS __attribute__((address_space(3)))

__device__ inline uint16_t f2b(float f) {
    uint32_t x = __float_as_uint(f);
    uint32_t r = (x + 0x7fffu + ((x >> 16) & 1u)) >> 16;
    return (uint16_t)r;
}

// ---------------------------------------------------------------- convert fp32 -> fp8 e4m3 (x64 prescale)
__global__ void cvt8_kernel(const float* __restrict__ in, uint2* __restrict__ out, size_t n8) {
    size_t stride = (size_t)gridDim.x * blockDim.x;
    for (size_t i = (size_t)blockIdx.x * blockDim.x + threadIdx.x; i < n8; i += stride) {
        const float4* p = (const float4*)(in + i * 8);
        float4 a = p[0], b = p[1];
        int w0 = __builtin_amdgcn_cvt_pk_fp8_f32(a.x * 64.f, a.y * 64.f, 0, false);
        w0 = __builtin_amdgcn_cvt_pk_fp8_f32(a.z * 64.f, a.w * 64.f, w0, true);
        int w1 = __builtin_amdgcn_cvt_pk_fp8_f32(b.x * 64.f, b.y * 64.f, 0, false);
        w1 = __builtin_amdgcn_cvt_pk_fp8_f32(b.z * 64.f, b.w * 64.f, w1, true);
        out[i] = make_uint2((unsigned)w0, (unsigned)w1);
    }
}

// ---------------------------------------------------------------- fp8 MX GEMM + fused LSE partials
// R10: tile 256x256, 8 waves (2M x 4N), per-wave 128x64 (acc=128 AGPR) ->
// DS-read 24 B/MFMA (vs R8 32) + B-panel reuse. K staged in PAIRS (128-B LDS
// rows) -> the R2/R3-measured-ZERO XOR swizzle (row&7)<<4 with m201 staging:
// 8 lanes cover one contiguous 128-B row (coalesced, 16 lines/instr), dest
// linear. 2 pair-buffers (128 KB, 1 block/CU, launch_bounds(512,2)).
// Stage p+1 at top of p; one vmcnt(0)+barrier per pair (128 K).
// Epilogue: 4-phase [64][132] LDS transpose, M=0 partials.

#define SC8 0x7F7F7F7F

#define MFMA8(aa, bb, cc) cc = __builtin_amdgcn_mfma_scale_f32_32x32x64_f8f6f4( \
        aa, bb, cc, 0, 0, 0, SC8, 0, SC8)

__device__ __forceinline__ i32x8 frag_read(const char* region, int row, int ob) {
    const int swz = (row & 7) << 4;
    const char* rp = region + row * 128;
    i32x4 lo = *(const i32x4*)(rp + (ob ^ swz));
    i32x4 hi = *(const i32x4*)(rp + ((ob + 16) ^ swz));
    i32x8 f;
    f[0] = lo[0]; f[1] = lo[1]; f[2] = lo[2]; f[3] = lo[3];
    f[4] = hi[0]; f[5] = hi[1]; f[6] = hi[2]; f[7] = hi[3];
    return f;
}

__global__ __launch_bounds__(512, 2)
void flce_gemm_fp8(const uint8_t* __restrict__ X8, const uint8_t* __restrict__ W8,
                   const long long* __restrict__ target,
                   float2* __restrict__ partials, float* __restrict__ tgt_logit,
                   int BT, int H, int V, int nrb) {
    __shared__ __align__(16) char smem[131072];   // buf i: A at i*65536, B at +32768
#define ABUF(i) (smem + (i) * 65536)
#define BBUF(i) (smem + (i) * 65536 + 32768)

    const int tid = threadIdx.x;
    const int lane = tid & 63, wave = tid >> 6;
    const int wr = wave >> 2, wc = wave & 3;     // 2(M) x 4(N)
    const int l31 = lane & 31;
    const int kq = lane >> 5;                    // fragment k-quarter (0/1)
    const int NP = H / 128;                      // k-pairs

    // bijective XCD swizzle (m204), rb-fastest (nwg=2000, %8==0)
    const int nwg = gridDim.x;
    const int q = nwg >> 3, rres = nwg & 7;
    const int xcd = blockIdx.x & 7, idx = blockIdx.x >> 3;
    const int wgid = (xcd < rres ? xcd * (q + 1) : rres * (q + 1) + (xcd - rres) * q) + idx;
    const int rb = wgid % nrb, cb = wgid / nrb;
    const int brow = rb * 256, bcol = cb * 256;

    const uint8_t* XA = X8 + (size_t)brow * H;
    const uint8_t* WB = W8 + (size_t)bcol * H;

    // staging (m201 pattern): instr j covers rows wave*32+j*8 .. +8, one full
    // 128-B run per 8 lanes, XOR-permuted source; dest linear (lane*16).
    const size_t srcOff = (size_t)(wave * 32 + (lane >> 3)) * H
                        + (size_t)(((lane & 7) ^ (lane >> 3)) * 16);
    const int dstOff = wave * 32 * 128 + lane * 16;
    const size_t h8 = (size_t)8 * H;

#define STG(gp, lp) __builtin_amdgcn_global_load_lds( \
        (const GLOBAL_AS uint32_t*)(gp), (LDS_AS uint32_t*)(lp), 16, 0, 0)
#define STAGE_PAIR(Ad, Bd, pk) do { \
        STG(XA + (pk) + srcOff,          (Ad) + dstOff); \
        STG(XA + (pk) + srcOff + h8,     (Ad) + dstOff + 1024); \
        STG(XA + (pk) + srcOff + 2*h8,   (Ad) + dstOff + 2048); \
        STG(XA + (pk) + srcOff + 3*h8,   (Ad) + dstOff + 3072); \
        STG(WB + (pk) + srcOff,          (Bd) + dstOff); \
        STG(WB + (pk) + srcOff + h8,     (Bd) + dstOff + 1024); \
        STG(WB + (pk) + srcOff + 2*h8,   (Bd) + dstOff + 2048); \
        STG(WB + (pk) + srcOff + 3*h8,   (Bd) + dstOff + 3072); \
    } while (0)

    f32x16 acc[4][2] = {};   // [m-frag 0..3][n-frag 0..1], all indices compile-time

    char *Ac = ABUF(0), *An = ABUF(1);
    char *Bc = BBUF(0), *Bn = BBUF(1);

    // ---- prologue
    STAGE_PAIR(Ac, Bc, 0);
    asm volatile("s_waitcnt vmcnt(0)" ::: "memory");
    __builtin_amdgcn_s_barrier();

    const int arow = wr * 128 + l31;
    const int brow_f = wc * 64 + l31;

    for (int p = 0; p < NP; ++p) {
        if (p + 1 < NP) STAGE_PAIR(An, Bn, (size_t)(p + 1) * 128);

#pragma unroll
        for (int ks = 0; ks < 2; ++ks) {
            const int ob = ks * 64 + kq * 32;
            i32x8 a0 = frag_read(Ac, arow, ob);
            i32x8 a1 = frag_read(Ac, arow + 32, ob);
            i32x8 a2 = frag_read(Ac, arow + 64, ob);
            i32x8 a3 = frag_read(Ac, arow + 96, ob);
            i32x8 b0 = frag_read(Bc, brow_f, ob);
            i32x8 b1 = frag_read(Bc, brow_f + 32, ob);
            __builtin_amdgcn_s_setprio(1);
            MFMA8(a0, b0, acc[0][0]); MFMA8(a0, b1, acc[0][1]);
            MFMA8(a1, b0, acc[1][0]); MFMA8(a1, b1, acc[1][1]);
            MFMA8(a2, b0, acc[2][0]); MFMA8(a2, b1, acc[2][1]);
            MFMA8(a3, b0, acc[3][0]); MFMA8(a3, b1, acc[3][1]);
            __builtin_amdgcn_s_setprio(0);
        }

        asm volatile("s_waitcnt vmcnt(0)" ::: "memory");  // p+1 landed (issued ~full pair ago)
        __builtin_amdgcn_s_barrier();
        char* t0 = Ac; Ac = An; An = t0;
        char* t1 = Bc; Bc = Bn; Bn = t1;
    }

    // ---- epilogue: 4 phases of 64 rows; [64][132] LDS transpose; M=0 partials
    __syncthreads();
    float* reg = (float*)smem;                    // [64][132] = 33792 B
    int* tgt_l = (int*)(smem + 33792);
    if (tid < 256) {
        long long tt = target[brow + tid];
        if (tt < 0) tt = 0;
        if (tt >= V) tt = (long long)V - 1;
        tgt_l[tid] = (int)tt;
    }
    __syncthreads();

    const float inv = 1.0f / 4096.0f;
    const int c0 = wc * 64 + l31;
#pragma unroll
    for (int qp = 0; qp < 4; ++qp) {
        if (wr == (qp >> 1)) {                    // writers: 4 waves (all wc)
#pragma unroll
            for (int mh = 0; mh < 2; ++mh) {
                const int m = (qp & 1) * 2 + mh;
#pragma unroll
                for (int j = 0; j < 16; ++j) {
                    int rif = (j & 3) + 8 * (j >> 2) + 4 * kq;
                    int rl = mh * 32 + rif;
                    int grow = qp * 64 + rl;
                    int tc = tgt_l[grow] - bcol;
                    float v0 = acc[m][0][j] * inv;
                    float v1 = acc[m][1][j] * inv;
                    if (tc == c0) tgt_logit[brow + grow] = v0;
                    if (tc == c0 + 32) tgt_logit[brow + grow] = v1;
                    reg[rl * 132 + wc * 32 + l31] = __expf(v0) + __expf(v1);
                }
            }
        }
        __syncthreads();
        if (wave == qp) {                         // reader wave sums 64 rows x 128 cols
            const f32x4* rp = (const f32x4*)(reg + lane * 132);
            f32x4 s4 = {0.f, 0.f, 0.f, 0.f};
#pragma unroll
            for (int c = 0; c < 32; ++c) {
                f32x4 v = rp[c];
                s4[0] += v[0]; s4[1] += v[1]; s4[2] += v[2]; s4[3] += v[3];
            }
            float S = (s4[0] + s4[1]) + (s4[2] + s4[3]);
            partials[(size_t)cb * BT + brow + qp * 64 + lane] = make_float2(0.f, S);
        }
        __syncthreads();
    }
#undef ABUF
#undef BBUF
#undef STG
#undef STAGE_PAIR
}

// ---------------------------------------------------------------- fp32 fallback (128^2, m97 structure)
__global__ void flce_gemm_f32(const float* __restrict__ X, const float* __restrict__ Wf,
                              const long long* __restrict__ target,
                              float2* __restrict__ partials, float* __restrict__ tgt_logit,
                              int BT, int H, int V, int nrb) {
    __shared__ uint16_t As[128 * 32];
    __shared__ uint16_t Bs[128 * 32];
    __shared__ float red_m[128][2];
    __shared__ float red_s[128][2];
    __shared__ int tgt_l[128];

    const int tid = threadIdx.x;
    const int wave = tid >> 6, lane = tid & 63;
    const int wr = wave >> 1, wc = wave & 1;
    const int l16 = lane & 15, lh = lane >> 4;
    const int bid = blockIdx.x;
    const int rb = bid % nrb, cb = bid / nrb;
    const int brow = rb * 128, bcol = cb * 128;

    if (tid < 128) {
        long long t = target[brow + tid];
        if (t < 0) t = 0;
        if (t >= V) t = (long long)V - 1;
        tgt_l[tid] = (int)t;
    }

    f32x4 acc[4][4] = {};
    for (int k0 = 0; k0 < H; k0 += 32) {
        __syncthreads();
#pragma unroll
        for (int j = 0; j < 4; ++j) {
            int fi = tid + j * 256;
            int row = fi >> 3;
            int kk = (fi & 7) << 2;
            float4 av = *(const float4*)(X + (size_t)(brow + row) * H + k0 + kk);
            float4 bv = *(const float4*)(Wf + (size_t)(bcol + row) * H + k0 + kk);
            u16x4 au, bu;
            au[0] = f2b(av.x); au[1] = f2b(av.y); au[2] = f2b(av.z); au[3] = f2b(av.w);
            bu[0] = f2b(bv.x); bu[1] = f2b(bv.y); bu[2] = f2b(bv.z); bu[3] = f2b(bv.w);
            *(u16x4*)&As[row * 32 + kk] = au;
            *(u16x4*)&Bs[row * 32 + kk] = bu;
        }
        __syncthreads();
        bf16x8 af[4], bf[4];
#pragma unroll
        for (int m = 0; m < 4; ++m)
            af[m] = *(const bf16x8*)&As[(wr * 64 + m * 16 + l16) * 32 + lh * 8];
#pragma unroll
        for (int n = 0; n < 4; ++n)
            bf[n] = *(const bf16x8*)&Bs[(wc * 64 + n * 16 + l16) * 32 + lh * 8];
#pragma unroll
        for (int m = 0; m < 4; ++m)
#pragma unroll
            for (int n = 0; n < 4; ++n)
                acc[m][n] = __builtin_amdgcn_mfma_f32_16x16x32_bf16(af[m], bf[n], acc[m][n], 0, 0, 0);
    }
#pragma unroll
    for (int m = 0; m < 4; ++m) {
#pragma unroll
        for (int r = 0; r < 4; ++r) {
            int rowl = wr * 64 + m * 16 + lh * 4 + r;
            int tc = tgt_l[rowl] - bcol;
            float mx = -INFINITY;
#pragma unroll
            for (int n = 0; n < 4; ++n) {
                float v = acc[m][n][r];
                if (tc == wc * 64 + n * 16 + l16) tgt_logit[brow + rowl] = v;
                mx = fmaxf(mx, v);
            }
#pragma unroll
            for (int d = 1; d < 16; d <<= 1) mx = fmaxf(mx, __shfl_xor(mx, d));
            float s = 0.f;
#pragma unroll
            for (int n = 0; n < 4; ++n) s += __expf(acc[m][n][r] - mx);
#pragma unroll
            for (int d = 1; d < 16; d <<= 1) s += __shfl_xor(s, d);
            if (l16 == 0) { red_m[rowl][wc] = mx; red_s[rowl][wc] = s; }
        }
    }
    __syncthreads();
    if (tid < 128) {
        float m0 = red_m[tid][0], m1 = red_m[tid][1];
        float s0 = red_s[tid][0], s1 = red_s[tid][1];
        float M = fmaxf(m0, m1);
        float S = s0 * __expf(m0 - M) + s1 * __expf(m1 - M);
        partials[(size_t)cb * BT + brow + tid] = make_float2(M, S);
    }
}

// ---------------------------------------------------------------- per-row LSE merge + block sums
__global__ void flce_reduce(const float2* __restrict__ partials,
                            const float* __restrict__ tgt_logit,
                            const long long* __restrict__ target,
                            float2* __restrict__ bsums, int BT, int NCB) {
    int row = blockIdx.x * blockDim.x + threadIdx.x;
    float M = -INFINITY, S = 0.f;
    for (int cbi = 0; cbi < NCB; ++cbi) {
        float2 p = partials[(size_t)cbi * BT + row];
        float Mn = fmaxf(M, p.x);
        S = S * __expf(M - Mn) + p.y * __expf(p.x - Mn);
        M = Mn;
    }
    float lse = M + __logf(S);
    bool valid = (target[row] != -100);
    float nll = valid ? (lse - tgt_logit[row]) : 0.f;
    float cnt = valid ? 1.f : 0.f;
#pragma unroll
    for (int d = 1; d < 64; d <<= 1) { nll += __shfl_xor(nll, d); cnt += __shfl_xor(cnt, d); }
    __shared__ float sm[8][2];
    int w = threadIdx.x >> 6;
    if ((threadIdx.x & 63) == 0) { sm[w][0] = nll; sm[w][1] = cnt; }
    __syncthreads();
    if (threadIdx.x == 0) {
        float sn = 0.f, sc = 0.f;
        int nw = blockDim.x >> 6;
        for (int i = 0; i < nw; ++i) { sn += sm[i][0]; sc += sm[i][1]; }
        bsums[blockIdx.x] = make_float2(sn, sc);
    }
}

__global__ void flce_final(const float2* __restrict__ bsums, int nb, float* __restrict__ out) {
    if (blockIdx.x == 0 && threadIdx.x == 0) {
        float sn = 0.f, sc = 0.f;
        for (int i = 0; i < nb; ++i) { sn += bsums[i].x; sc += bsums[i].y; }
        out[0] = sn / sc;
    }
}

// ---------------------------------------------------------------- launch
extern "C" void kernel_launch(void* const* d_in, const int* in_sizes, int n_in,
                              void* d_out, int out_size, void* d_ws, size_t ws_size,
                              hipStream_t stream) {
    const float* x = (const float*)d_in[0];
    const float* w = (const float*)d_in[1];
    const long long* target = (const long long*)d_in[2];
    float* out = (float*)d_out;

    const int BT = in_sizes[2];
    const int H = in_sizes[0] / BT;
    const int V = in_sizes[1] / H;
    const int nred = BT / 256;

    char* ws = (char*)d_ws;
    size_t szW = (size_t)V * H;            // fp8: 1 B/elem
    size_t szX = (size_t)BT * H;
    const int nrb = BT / 256;              // 16
    const int ncb = V / 256;               // 125
    size_t szPart = (size_t)ncb * BT * sizeof(float2);
    size_t szTgt = (size_t)BT * sizeof(float);
    size_t szB = (size_t)nred * sizeof(float2);

    bool use8 = ws_size >= szW + szX + szPart + szTgt + szB;

    if (use8) {
        uint8_t* W8 = (uint8_t*)ws;
        uint8_t* X8 = (uint8_t*)(ws + szW);
        float2* partials = (float2*)(ws + szW + szX);
        float* tgtlog = (float*)(ws + szW + szX + szPart);
        float2* bsums = (float2*)(ws + szW + szX + szPart + szTgt);

        hipLaunchKernelGGL(cvt8_kernel, dim3(1024), dim3(256), 0, stream,
                           x, (uint2*)X8, (size_t)BT * H / 8);
        hipLaunchKernelGGL(cvt8_kernel, dim3(4096), dim3(256), 0, stream,
                           w, (uint2*)W8, (size_t)V * H / 8);
        hipLaunchKernelGGL(flce_gemm_fp8, dim3(nrb * ncb), dim3(512), 0, stream,
                           X8, W8, target, partials, tgtlog, BT, H, V, nrb);
        hipLaunchKernelGGL(flce_reduce, dim3(BT / 256), dim3(256), 0, stream,
                           partials, tgtlog, target, bsums, BT, ncb);
        hipLaunchKernelGGL(flce_final, dim3(1), dim3(64), 0, stream, bsums, nred, out);
    } else {
        const int nrb1 = BT / 128, ncb1 = V / 128;
        float2* partials = (float2*)ws;
        float* tgtlog = (float*)(ws + (size_t)ncb1 * BT * sizeof(float2));
        float2* bsums = (float2*)(ws + (size_t)ncb1 * BT * sizeof(float2) + szTgt);
        hipLaunchKernelGGL(flce_gemm_f32, dim3(nrb1 * ncb1), dim3(256), 0, stream,
                           x, w, target, partials, tgtlog, BT, H, V, nrb1);
        hipLaunchKernelGGL(flce_reduce, dim3(BT / 256), dim3(256), 0, stream,
                           partials, tgtlog, target, bsums, BT, ncb1);
        hipLaunchKernelGGL(flce_final, dim3(1), dim3(64), 0, stream, bsums, nred, out);
    }
}